// Round 1
// baseline (272.952 us; speedup 1.0000x reference)
//
#include <hip/hip_runtime.h>

// KAN layer: D=4096 per-edge MLPs 64->64->64->64 (relu), scalar input per edge,
// output layer reduces over (i_in, h2) with wout.
// Round 1: f32 VALU baseline. One block per edge, thread = batch row.

#define D_EDGES 4096
#define BSZ     256
#define HDIM    64

// partial layout: partial[o][i][b]  (64 x 64 x 256 floats = 4 MB)
__global__ __launch_bounds__(256) void kan_edge_mlp(
    const float* __restrict__ x,     // (256, 64)
    const float* __restrict__ w0,    // (64, 64, 64) -> (D, 64)
    const float* __restrict__ b0,    // (D, 64)
    const float* __restrict__ w1,    // (D, 64, 64)
    const float* __restrict__ b1,    // (D, 64)
    const float* __restrict__ w2,    // (D, 64, 64)
    const float* __restrict__ b2,    // (D, 64)
    const float* __restrict__ wout,  // (64, 4096)
    float* __restrict__ partial)     // (64, 64, 256)
{
    const int d  = blockIdx.x;
    const int o  = d >> 6;
    const int ii = d & 63;
    const int t  = threadIdx.x;      // batch index b

    __shared__ float sW1[4096];
    __shared__ float sW2[4096];
    __shared__ float sw0[64];
    __shared__ float sb0[64];
    __shared__ float sb1[64];
    __shared__ float sb2[64];
    __shared__ float swo[64];

    // ---- stage weights (coalesced float4) ----
    const float4* w1v = (const float4*)(w1 + (size_t)d * 4096);
    const float4* w2v = (const float4*)(w2 + (size_t)d * 4096);
    float4* sW1v = (float4*)sW1;
    float4* sW2v = (float4*)sW2;
#pragma unroll
    for (int k = 0; k < 4; ++k) {
        sW1v[t + k * 256] = w1v[t + k * 256];
        sW2v[t + k * 256] = w2v[t + k * 256];
    }
    if (t < 64) {
        sw0[t] = w0[(size_t)d * 64 + t];
        sb0[t] = b0[(size_t)d * 64 + t];
        sb1[t] = b1[(size_t)d * 64 + t];
        sb2[t] = b2[(size_t)d * 64 + t];
        swo[t] = wout[(size_t)o * 4096 + ii * 64 + t];
    }
    __syncthreads();

    const float xb = x[t * 64 + ii];

    // ---- layer 0: h0[j] = relu(x_b * w0[d,j] + b0[d,j]) ----
    float h0[64];
#pragma unroll
    for (int j = 0; j < 64; ++j)
        h0[j] = fmaxf(fmaf(xb, sw0[j], sb0[j]), 0.f);

    // ---- layer 1: h1[oo] = relu(sum_i W1[oo,i]*h0[i] + b1[oo]) ----
    float h1[64];
#pragma unroll
    for (int oo = 0; oo < 64; ++oo) {
        float acc = sb1[oo];
        const float4* row = (const float4*)(sW1 + oo * 64);
#pragma unroll
        for (int i4 = 0; i4 < 16; ++i4) {
            float4 w = row[i4];
            acc = fmaf(w.x, h0[i4 * 4 + 0], acc);
            acc = fmaf(w.y, h0[i4 * 4 + 1], acc);
            acc = fmaf(w.z, h0[i4 * 4 + 2], acc);
            acc = fmaf(w.w, h0[i4 * 4 + 3], acc);
        }
        h1[oo] = fmaxf(acc, 0.f);
    }

    // ---- layer 2 fused with output dot: out = sum_oo relu(W2[oo,:].h1 + b2[oo]) * wout[o, ii*64+oo] ----
    float outv = 0.f;
#pragma unroll
    for (int oo = 0; oo < 64; ++oo) {
        float acc = sb2[oo];
        const float4* row = (const float4*)(sW2 + oo * 64);
#pragma unroll
        for (int i4 = 0; i4 < 16; ++i4) {
            float4 w = row[i4];
            acc = fmaf(w.x, h1[i4 * 4 + 0], acc);
            acc = fmaf(w.y, h1[i4 * 4 + 1], acc);
            acc = fmaf(w.z, h1[i4 * 4 + 2], acc);
            acc = fmaf(w.w, h1[i4 * 4 + 3], acc);
        }
        outv = fmaf(fmaxf(acc, 0.f), swo[oo], outv);
    }

    // coalesced: lanes differ in t
    partial[(size_t)o * (64 * 256) + (size_t)ii * 256 + t] = outv;
}

// Deterministic reduction over ii: y[b,o] = bout[o] + sum_ii partial[o][ii][b]
__global__ __launch_bounds__(256) void kan_reduce(
    const float* __restrict__ partial,
    const float* __restrict__ bout,
    float* __restrict__ y)
{
    const int o = blockIdx.x;    // 64
    const int b = threadIdx.x;   // 256
    float acc = bout[o];
    const float* p = partial + (size_t)o * (64 * 256) + b;
#pragma unroll
    for (int i = 0; i < 64; ++i)
        acc += p[i * 256];
    y[b * 64 + o] = acc;
}

// ---- atomic fallback (only if ws too small; still deterministic per-config) ----
__global__ __launch_bounds__(256) void kan_init_out(const float* __restrict__ bout,
                                                    float* __restrict__ y)
{
    const int idx = blockIdx.x * 256 + threadIdx.x;   // 16384 outputs
    y[idx] = bout[idx & 63];
}

__global__ __launch_bounds__(256) void kan_edge_mlp_atomic(
    const float* __restrict__ x,
    const float* __restrict__ w0,
    const float* __restrict__ b0,
    const float* __restrict__ w1,
    const float* __restrict__ b1,
    const float* __restrict__ w2,
    const float* __restrict__ b2,
    const float* __restrict__ wout,
    float* __restrict__ y)
{
    const int d  = blockIdx.x;
    const int o  = d >> 6;
    const int ii = d & 63;
    const int t  = threadIdx.x;

    __shared__ float sW1[4096];
    __shared__ float sW2[4096];
    __shared__ float sw0[64];
    __shared__ float sb0[64];
    __shared__ float sb1[64];
    __shared__ float sb2[64];
    __shared__ float swo[64];

    const float4* w1v = (const float4*)(w1 + (size_t)d * 4096);
    const float4* w2v = (const float4*)(w2 + (size_t)d * 4096);
    float4* sW1v = (float4*)sW1;
    float4* sW2v = (float4*)sW2;
#pragma unroll
    for (int k = 0; k < 4; ++k) {
        sW1v[t + k * 256] = w1v[t + k * 256];
        sW2v[t + k * 256] = w2v[t + k * 256];
    }
    if (t < 64) {
        sw0[t] = w0[(size_t)d * 64 + t];
        sb0[t] = b0[(size_t)d * 64 + t];
        sb1[t] = b1[(size_t)d * 64 + t];
        sb2[t] = b2[(size_t)d * 64 + t];
        swo[t] = wout[(size_t)o * 4096 + ii * 64 + t];
    }
    __syncthreads();

    const float xb = x[t * 64 + ii];

    float h0[64];
#pragma unroll
    for (int j = 0; j < 64; ++j)
        h0[j] = fmaxf(fmaf(xb, sw0[j], sb0[j]), 0.f);

    float h1[64];
#pragma unroll
    for (int oo = 0; oo < 64; ++oo) {
        float acc = sb1[oo];
        const float4* row = (const float4*)(sW1 + oo * 64);
#pragma unroll
        for (int i4 = 0; i4 < 16; ++i4) {
            float4 w = row[i4];
            acc = fmaf(w.x, h0[i4 * 4 + 0], acc);
            acc = fmaf(w.y, h0[i4 * 4 + 1], acc);
            acc = fmaf(w.z, h0[i4 * 4 + 2], acc);
            acc = fmaf(w.w, h0[i4 * 4 + 3], acc);
        }
        h1[oo] = fmaxf(acc, 0.f);
    }

    float outv = 0.f;
#pragma unroll
    for (int oo = 0; oo < 64; ++oo) {
        float acc = sb2[oo];
        const float4* row = (const float4*)(sW2 + oo * 64);
#pragma unroll
        for (int i4 = 0; i4 < 16; ++i4) {
            float4 w = row[i4];
            acc = fmaf(w.x, h1[i4 * 4 + 0], acc);
            acc = fmaf(w.y, h1[i4 * 4 + 1], acc);
            acc = fmaf(w.z, h1[i4 * 4 + 2], acc);
            acc = fmaf(w.w, h1[i4 * 4 + 3], acc);
        }
        outv = fmaf(fmaxf(acc, 0.f), swo[oo], outv);
    }

    atomicAdd(&y[t * 64 + o], outv);
}

extern "C" void kernel_launch(void* const* d_in, const int* in_sizes, int n_in,
                              void* d_out, int out_size, void* d_ws, size_t ws_size,
                              hipStream_t stream) {
    const float* x    = (const float*)d_in[0];
    const float* w0   = (const float*)d_in[1];
    const float* b0   = (const float*)d_in[2];
    const float* w1   = (const float*)d_in[3];
    const float* b1   = (const float*)d_in[4];
    const float* w2   = (const float*)d_in[5];
    const float* b2   = (const float*)d_in[6];
    const float* wout = (const float*)d_in[7];
    const float* bout = (const float*)d_in[8];
    float* y = (float*)d_out;

    const size_t partial_bytes = (size_t)64 * 64 * 256 * sizeof(float); // 4 MB

    if (ws_size >= partial_bytes) {
        float* partial = (float*)d_ws;
        kan_edge_mlp<<<D_EDGES, BSZ, 0, stream>>>(x, w0, b0, w1, b1, w2, b2, wout, partial);
        kan_reduce<<<64, BSZ, 0, stream>>>(partial, bout, y);
    } else {
        kan_init_out<<<64, BSZ, 0, stream>>>(bout, y);
        kan_edge_mlp_atomic<<<D_EDGES, BSZ, 0, stream>>>(x, w0, b0, w1, b1, w2, b2, wout, y);
    }
}

// Round 2
// 66.500 us; speedup vs baseline: 4.1045x; 4.1045x over previous
//
#include <hip/hip_runtime.h>

// KAN layer, round 2: per-edge hidden GEMMs on MFMA bf16 (16x16x32) with
// split-precision activations (hi+lo bf16 -> 2 MFMAs, ~f32-accurate).
// Layer0 (scalar outer product) and output reduction stay f32 VALU.
//
// Per block (edge d): swapped GEMM D[n][m] = sum_k W[n][k] * H[m][k]
//   A-frag = W rows [n][k]  (global layout as-is)
//   B-frag = H rows [m][k]
//   C/D: col(m)=lane&15, row(n)=(lane>>4)*4+reg  -> lane holds 4 consecutive n
// All LDS tiles XOR-swizzled: byte ^= (row&7)<<4 (row stride 128B).

#define D_EDGES 4096

typedef __attribute__((ext_vector_type(4))) float f32x4;
typedef __attribute__((ext_vector_type(8))) short bf16x8;

__device__ __forceinline__ unsigned f2bf(float f) {
    union { float f; unsigned u; } v; v.f = f;
    return (v.u + 0x7FFFu + ((v.u >> 16) & 1u)) >> 16;   // RNE
}
__device__ __forceinline__ float bf2f(unsigned h) {
    union { unsigned u; float f; } v; v.u = h << 16; return v.f;
}
__device__ __forceinline__ unsigned pk2(float a, float b) {
    return f2bf(a) | (f2bf(b) << 16);
}

__global__ __launch_bounds__(256, 3) void kan_mfma(
    const float* __restrict__ x,     // (256, 64)
    const float* __restrict__ w0g,   // (D, 64)
    const float* __restrict__ b0g,   // (D, 64)
    const float* __restrict__ w1g,   // (D, 64, 64)
    const float* __restrict__ b1g,   // (D, 64)
    const float* __restrict__ w2g,   // (D, 64, 64)
    const float* __restrict__ b2g,   // (D, 64)
    const float* __restrict__ woutg, // (64, 4096)
    float* __restrict__ outbuf,      // partial (D,256) or y (256,64)
    int atomic_mode)
{
    const int d = blockIdx.x, o = d >> 6, ii = d & 63;
    const int t = threadIdx.x;
    const int lane = t & 63, wv = t >> 6;

    __shared__ __align__(16) unsigned char Hhi[128 * 128]; // [m][k] bf16, swizzled
    __shared__ __align__(16) unsigned char Hlo[128 * 128];
    __shared__ __align__(16) unsigned char W1s[64 * 128];  // [n][k] bf16, swizzled
    __shared__ __align__(16) unsigned char W2s[64 * 128];
    __shared__ __align__(16) float sx[256];
    __shared__ __align__(16) float sw0[64], sb0[64], sb1[64], sb2[64], swo[64];

    // ---- stage W1, W2 -> bf16, swizzled (16 elems / thread / matrix) ----
    {
        const int orow = t >> 2, q = t & 3;
        const unsigned swz  = (unsigned)((orow & 7) << 4);
        const unsigned base = (unsigned)(orow * 128);
        const float* s1 = w1g + (size_t)d * 4096 + orow * 64 + q * 16;
        const float* s2 = w2g + (size_t)d * 4096 + orow * 64 + q * 16;

        float4 a0 = ((const float4*)s1)[0], a1 = ((const float4*)s1)[1];
        float4 a2 = ((const float4*)s1)[2], a3 = ((const float4*)s1)[3];
        uint4 u0 = { pk2(a0.x, a0.y), pk2(a0.z, a0.w), pk2(a1.x, a1.y), pk2(a1.z, a1.w) };
        uint4 u1 = { pk2(a2.x, a2.y), pk2(a2.z, a2.w), pk2(a3.x, a3.y), pk2(a3.z, a3.w) };
        *(uint4*)&W1s[base + ((unsigned)(q * 32)      ^ swz)] = u0;
        *(uint4*)&W1s[base + ((unsigned)(q * 32 + 16) ^ swz)] = u1;

        a0 = ((const float4*)s2)[0]; a1 = ((const float4*)s2)[1];
        a2 = ((const float4*)s2)[2]; a3 = ((const float4*)s2)[3];
        uint4 v0 = { pk2(a0.x, a0.y), pk2(a0.z, a0.w), pk2(a1.x, a1.y), pk2(a1.z, a1.w) };
        uint4 v1 = { pk2(a2.x, a2.y), pk2(a2.z, a2.w), pk2(a3.x, a3.y), pk2(a3.z, a3.w) };
        *(uint4*)&W2s[base + ((unsigned)(q * 32)      ^ swz)] = v0;
        *(uint4*)&W2s[base + ((unsigned)(q * 32 + 16) ^ swz)] = v1;
    }
    sx[t] = x[t * 64 + ii];
    if (t < 64) {
        sw0[t] = w0g[(size_t)d * 64 + t];
        sb0[t] = b0g[(size_t)d * 64 + t];
        sb1[t] = b1g[(size_t)d * 64 + t];
        sb2[t] = b2g[(size_t)d * 64 + t];
        swo[t] = woutg[(size_t)o * 4096 + ii * 64 + t];
    }
    __syncthreads();

    const f32x4 zero4 = { 0.f, 0.f, 0.f, 0.f };

    for (int hf = 0; hf < 2; ++hf) {
        // ---- layer 0: H0[m][j] = relu(x_b * w0[j] + b0[j]), split hi/lo ----
        {
            const int rl = t >> 1, j0 = (t & 1) * 32;
            const float xb = sx[hf * 128 + rl];
            const unsigned swz = (unsigned)((rl & 7) << 4);
            const unsigned rb  = (unsigned)(rl * 128);
#pragma unroll
            for (int c = 0; c < 8; ++c) {
                const int j = j0 + c * 4;
                float4 w  = *(const float4*)&sw0[j];
                float4 bb = *(const float4*)&sb0[j];
                float v0 = fmaxf(fmaf(xb, w.x, bb.x), 0.f);
                float v1 = fmaxf(fmaf(xb, w.y, bb.y), 0.f);
                float v2 = fmaxf(fmaf(xb, w.z, bb.z), 0.f);
                float v3 = fmaxf(fmaf(xb, w.w, bb.w), 0.f);
                unsigned h0 = f2bf(v0), h1 = f2bf(v1), h2 = f2bf(v2), h3 = f2bf(v3);
                uint2 hp = { h0 | (h1 << 16), h2 | (h3 << 16) };
                uint2 lp = { pk2(v0 - bf2f(h0), v1 - bf2f(h1)),
                             pk2(v2 - bf2f(h2), v3 - bf2f(h3)) };
                const unsigned a = rb + ((unsigned)(2 * j) ^ swz);
                *(uint2*)&Hhi[a] = hp;
                *(uint2*)&Hlo[a] = lp;
            }
        }
        __syncthreads();

        const int arow = lane & 15;            // within-tile row/col
        const int kb   = (lane >> 4) * 16;     // k-group byte offset
        const unsigned lswz = (unsigned)((lane & 7) << 4);

        // ---- layer 1 MFMA ----
        f32x4 acc[2][4];
#pragma unroll
        for (int i = 0; i < 2; ++i)
#pragma unroll
            for (int j = 0; j < 4; ++j) acc[i][j] = zero4;
        {
            bf16x8 wf[4][2];
#pragma unroll
            for (int nt = 0; nt < 4; ++nt)
#pragma unroll
                for (int ks = 0; ks < 2; ++ks)
                    wf[nt][ks] = *(const bf16x8*)&W1s[(nt * 16 + arow) * 128 +
                                    ((unsigned)(ks * 64 + kb) ^ lswz)];
#pragma unroll
            for (int mt2 = 0; mt2 < 2; ++mt2) {
                const unsigned rb = (unsigned)(((wv * 2 + mt2) * 16 + arow) * 128);
#pragma unroll
                for (int ks = 0; ks < 2; ++ks) {
                    const unsigned a = rb + ((unsigned)(ks * 64 + kb) ^ lswz);
                    bf16x8 bhi = *(const bf16x8*)&Hhi[a];
                    bf16x8 blo = *(const bf16x8*)&Hlo[a];
#pragma unroll
                    for (int nt = 0; nt < 4; ++nt) {
                        acc[mt2][nt] = __builtin_amdgcn_mfma_f32_16x16x32_bf16(
                            wf[nt][ks], blo, acc[mt2][nt], 0, 0, 0);
                        acc[mt2][nt] = __builtin_amdgcn_mfma_f32_16x16x32_bf16(
                            wf[nt][ks], bhi, acc[mt2][nt], 0, 0, 0);
                    }
                }
            }
        }
        __syncthreads();  // all H0 reads complete before overwrite

        // ---- H1 = relu(acc + b1), split hi/lo, write back ----
        {
            const int r0 = (lane >> 4) * 4;
#pragma unroll
            for (int mt2 = 0; mt2 < 2; ++mt2) {
                const int m = (wv * 2 + mt2) * 16 + arow;
                const unsigned rb  = (unsigned)(m * 128);
                const unsigned swz = (unsigned)((m & 7) << 4);
#pragma unroll
                for (int nt = 0; nt < 4; ++nt) {
                    float4 bv = *(const float4*)&sb1[nt * 16 + r0];
                    float v0 = fmaxf(acc[mt2][nt][0] + bv.x, 0.f);
                    float v1 = fmaxf(acc[mt2][nt][1] + bv.y, 0.f);
                    float v2 = fmaxf(acc[mt2][nt][2] + bv.z, 0.f);
                    float v3 = fmaxf(acc[mt2][nt][3] + bv.w, 0.f);
                    unsigned h0 = f2bf(v0), h1 = f2bf(v1), h2 = f2bf(v2), h3 = f2bf(v3);
                    uint2 hp = { h0 | (h1 << 16), h2 | (h3 << 16) };
                    uint2 lp = { pk2(v0 - bf2f(h0), v1 - bf2f(h1)),
                                 pk2(v2 - bf2f(h2), v3 - bf2f(h3)) };
                    const unsigned a = rb + ((unsigned)(2 * (nt * 16 + r0)) ^ swz);
                    *(uint2*)&Hhi[a] = hp;
                    *(uint2*)&Hlo[a] = lp;
                }
            }
        }
        __syncthreads();

        // ---- layer 2 MFMA ----
        f32x4 acc2[2][4];
#pragma unroll
        for (int i = 0; i < 2; ++i)
#pragma unroll
            for (int j = 0; j < 4; ++j) acc2[i][j] = zero4;
        {
            bf16x8 wf[4][2];
#pragma unroll
            for (int nt = 0; nt < 4; ++nt)
#pragma unroll
                for (int ks = 0; ks < 2; ++ks)
                    wf[nt][ks] = *(const bf16x8*)&W2s[(nt * 16 + arow) * 128 +
                                    ((unsigned)(ks * 64 + kb) ^ lswz)];
#pragma unroll
            for (int mt2 = 0; mt2 < 2; ++mt2) {
                const unsigned rb = (unsigned)(((wv * 2 + mt2) * 16 + arow) * 128);
#pragma unroll
                for (int ks = 0; ks < 2; ++ks) {
                    const unsigned a = rb + ((unsigned)(ks * 64 + kb) ^ lswz);
                    bf16x8 bhi = *(const bf16x8*)&Hhi[a];
                    bf16x8 blo = *(const bf16x8*)&Hlo[a];
#pragma unroll
                    for (int nt = 0; nt < 4; ++nt) {
                        acc2[mt2][nt] = __builtin_amdgcn_mfma_f32_16x16x32_bf16(
                            wf[nt][ks], blo, acc2[mt2][nt], 0, 0, 0);
                        acc2[mt2][nt] = __builtin_amdgcn_mfma_f32_16x16x32_bf16(
                            wf[nt][ks], bhi, acc2[mt2][nt], 0, 0, 0);
                    }
                }
            }
        }

        // ---- epilogue: p[m] = sum_n relu(acc2 + b2[n]) * swo[n] ----
        {
            const int r0 = (lane >> 4) * 4;
#pragma unroll
            for (int mt2 = 0; mt2 < 2; ++mt2) {
                float p = 0.f;
#pragma unroll
                for (int nt = 0; nt < 4; ++nt) {
                    float4 bv = *(const float4*)&sb2[nt * 16 + r0];
                    float4 wo = *(const float4*)&swo[nt * 16 + r0];
                    p = fmaf(fmaxf(acc2[mt2][nt][0] + bv.x, 0.f), wo.x, p);
                    p = fmaf(fmaxf(acc2[mt2][nt][1] + bv.y, 0.f), wo.y, p);
                    p = fmaf(fmaxf(acc2[mt2][nt][2] + bv.z, 0.f), wo.z, p);
                    p = fmaf(fmaxf(acc2[mt2][nt][3] + bv.w, 0.f), wo.w, p);
                }
                p += __shfl_xor(p, 16);
                p += __shfl_xor(p, 32);
                const int b = hf * 128 + (wv * 2 + mt2) * 16 + arow;
                if (lane < 16) {
                    if (atomic_mode) atomicAdd(&outbuf[b * 64 + o], p);
                    else             outbuf[(size_t)d * 256 + b] = p;
                }
            }
        }
        __syncthreads();  // layer2 H reads done before next half's layer0 writes
    }
}

// Deterministic reduction over ii: y[b,o] = bout[o] + sum_ii partial[(o*64+ii)*256 + b]
__global__ __launch_bounds__(256) void kan_reduce(
    const float* __restrict__ partial,
    const float* __restrict__ bout,
    float* __restrict__ y)
{
    const int o = blockIdx.x;    // 64
    const int b = threadIdx.x;   // 256
    float acc = bout[o];
    const float* p = partial + (size_t)o * (64 * 256) + b;
#pragma unroll
    for (int i = 0; i < 64; ++i)
        acc += p[i * 256];
    y[b * 64 + o] = acc;
}

__global__ __launch_bounds__(256) void kan_init_out(const float* __restrict__ bout,
                                                    float* __restrict__ y)
{
    const int idx = blockIdx.x * 256 + threadIdx.x;
    y[idx] = bout[idx & 63];
}

extern "C" void kernel_launch(void* const* d_in, const int* in_sizes, int n_in,
                              void* d_out, int out_size, void* d_ws, size_t ws_size,
                              hipStream_t stream) {
    const float* x    = (const float*)d_in[0];
    const float* w0   = (const float*)d_in[1];
    const float* b0   = (const float*)d_in[2];
    const float* w1   = (const float*)d_in[3];
    const float* b1   = (const float*)d_in[4];
    const float* w2   = (const float*)d_in[5];
    const float* b2   = (const float*)d_in[6];
    const float* wout = (const float*)d_in[7];
    const float* bout = (const float*)d_in[8];
    float* y = (float*)d_out;

    const size_t partial_bytes = (size_t)D_EDGES * 256 * sizeof(float); // 4 MB

    if (ws_size >= partial_bytes) {
        float* partial = (float*)d_ws;
        kan_mfma<<<D_EDGES, 256, 0, stream>>>(x, w0, b0, w1, b1, w2, b2, wout, partial, 0);
        kan_reduce<<<64, 256, 0, stream>>>(partial, bout, y);
    } else {
        kan_init_out<<<64, 256, 0, stream>>>(bout, y);
        kan_mfma<<<D_EDGES, 256, 0, stream>>>(x, w0, b0, w1, b1, w2, b2, wout, y, 1);
    }
}

// Round 3
// 45.591 us; speedup vs baseline: 5.9869x; 1.4586x over previous
//
#include <hip/hip_runtime.h>
#include <hip/hip_bf16.h>

// KAN layer, round 3: pure-bf16 MFMA hidden layers (no hi/lo split).
// cvt_pk-friendly conversions, 16B layer-0 stores, Hs single buffer -> 34 KB LDS
// -> 4 blocks/CU. Swapped GEMM D[n][m] = W[n][k]*H[m][k]; XOR swizzle (row&7)<<4.

#define D_EDGES 4096

typedef __attribute__((ext_vector_type(4))) float f32x4;
typedef __attribute__((ext_vector_type(8))) short bf16x8;

__device__ __forceinline__ unsigned pk2(float a, float b) {
    __hip_bfloat162 h = __float22bfloat162_rn(float2{a, b});
    return *reinterpret_cast<unsigned*>(&h);
}

__global__ __launch_bounds__(256, 4) void kan_mfma(
    const float* __restrict__ x,     // (256, 64)
    const float* __restrict__ w0g,   // (D, 64)
    const float* __restrict__ b0g,   // (D, 64)
    const float* __restrict__ w1g,   // (D, 64, 64)
    const float* __restrict__ b1g,   // (D, 64)
    const float* __restrict__ w2g,   // (D, 64, 64)
    const float* __restrict__ b2g,   // (D, 64)
    const float* __restrict__ woutg, // (64, 4096)
    float* __restrict__ outbuf,      // partial (D,256) or y (256,64)
    int atomic_mode)
{
    const int d = blockIdx.x, o = d >> 6, ii = d & 63;
    const int t = threadIdx.x;
    const int lane = t & 63, wv = t >> 6;

    __shared__ __align__(16) unsigned char Hs[128 * 128];   // [m][k] bf16, swizzled
    __shared__ __align__(16) unsigned char W1s[64 * 128];   // [n][k] bf16, swizzled
    __shared__ __align__(16) unsigned char W2s[64 * 128];
    __shared__ __align__(16) float sx[256];
    __shared__ __align__(16) float sw0[64], sb0[64], sb1[64], sb2[64], swo[64];

    // ---- stage W1, W2 -> bf16, swizzled (16 elems / thread / matrix) ----
    {
        const int orow = t >> 2, q = t & 3;
        const unsigned swz  = (unsigned)((orow & 7) << 4);
        const unsigned base = (unsigned)(orow * 128);
        const float* s1 = w1g + (size_t)d * 4096 + orow * 64 + q * 16;
        const float* s2 = w2g + (size_t)d * 4096 + orow * 64 + q * 16;

        float4 a0 = ((const float4*)s1)[0], a1 = ((const float4*)s1)[1];
        float4 a2 = ((const float4*)s1)[2], a3 = ((const float4*)s1)[3];
        uint4 u0 = { pk2(a0.x, a0.y), pk2(a0.z, a0.w), pk2(a1.x, a1.y), pk2(a1.z, a1.w) };
        uint4 u1 = { pk2(a2.x, a2.y), pk2(a2.z, a2.w), pk2(a3.x, a3.y), pk2(a3.z, a3.w) };
        *(uint4*)&W1s[base + ((unsigned)(q * 32)      ^ swz)] = u0;
        *(uint4*)&W1s[base + ((unsigned)(q * 32 + 16) ^ swz)] = u1;

        a0 = ((const float4*)s2)[0]; a1 = ((const float4*)s2)[1];
        a2 = ((const float4*)s2)[2]; a3 = ((const float4*)s2)[3];
        uint4 v0 = { pk2(a0.x, a0.y), pk2(a0.z, a0.w), pk2(a1.x, a1.y), pk2(a1.z, a1.w) };
        uint4 v1 = { pk2(a2.x, a2.y), pk2(a2.z, a2.w), pk2(a3.x, a3.y), pk2(a3.z, a3.w) };
        *(uint4*)&W2s[base + ((unsigned)(q * 32)      ^ swz)] = v0;
        *(uint4*)&W2s[base + ((unsigned)(q * 32 + 16) ^ swz)] = v1;
    }
    sx[t] = x[t * 64 + ii];
    if (t < 64) {
        sw0[t] = w0g[(size_t)d * 64 + t];
        sb0[t] = b0g[(size_t)d * 64 + t];
        sb1[t] = b1g[(size_t)d * 64 + t];
        sb2[t] = b2g[(size_t)d * 64 + t];
        swo[t] = woutg[(size_t)o * 4096 + ii * 64 + t];
    }
    __syncthreads();

    const f32x4 zero4 = { 0.f, 0.f, 0.f, 0.f };

    for (int hf = 0; hf < 2; ++hf) {
        // ---- layer 0: H0[m][j] = relu(x_b * w0[j] + b0[j]) -> bf16, 16B stores ----
        {
            const int m  = t & 127;
            const int cb = (t >> 7) * 32;
            const float xb = sx[hf * 128 + m];
            const unsigned swz = (unsigned)((m & 7) << 4);
            const unsigned rb  = (unsigned)(m * 128);
#pragma unroll
            for (int c = 0; c < 4; ++c) {
                const int j = cb + c * 8;
                float4 wA = *(const float4*)&sw0[j];
                float4 wB = *(const float4*)&sw0[j + 4];
                float4 bA = *(const float4*)&sb0[j];
                float4 bB = *(const float4*)&sb0[j + 4];
                float v0 = fmaxf(fmaf(xb, wA.x, bA.x), 0.f);
                float v1 = fmaxf(fmaf(xb, wA.y, bA.y), 0.f);
                float v2 = fmaxf(fmaf(xb, wA.z, bA.z), 0.f);
                float v3 = fmaxf(fmaf(xb, wA.w, bA.w), 0.f);
                float v4 = fmaxf(fmaf(xb, wB.x, bB.x), 0.f);
                float v5 = fmaxf(fmaf(xb, wB.y, bB.y), 0.f);
                float v6 = fmaxf(fmaf(xb, wB.z, bB.z), 0.f);
                float v7 = fmaxf(fmaf(xb, wB.w, bB.w), 0.f);
                uint4 u = { pk2(v0, v1), pk2(v2, v3), pk2(v4, v5), pk2(v6, v7) };
                *(uint4*)&Hs[rb + ((unsigned)(2 * j) ^ swz)] = u;
            }
        }
        __syncthreads();

        const int arow = lane & 15;
        const int kb   = (lane >> 4) * 16;     // byte offset of this lane's 8 k-elems
        const unsigned lswz = (unsigned)((lane & 7) << 4);

        // ---- layer 1 MFMA ----
        f32x4 acc[2][4];
#pragma unroll
        for (int i = 0; i < 2; ++i)
#pragma unroll
            for (int j = 0; j < 4; ++j) acc[i][j] = zero4;
        {
            bf16x8 wf[4][2];
#pragma unroll
            for (int nt = 0; nt < 4; ++nt)
#pragma unroll
                for (int ks = 0; ks < 2; ++ks)
                    wf[nt][ks] = *(const bf16x8*)&W1s[(nt * 16 + arow) * 128 +
                                    ((unsigned)(ks * 64 + kb) ^ lswz)];
#pragma unroll
            for (int mt2 = 0; mt2 < 2; ++mt2) {
                const unsigned rb = (unsigned)(((wv * 2 + mt2) * 16 + arow) * 128);
#pragma unroll
                for (int ks = 0; ks < 2; ++ks) {
                    bf16x8 bh = *(const bf16x8*)&Hs[rb + ((unsigned)(ks * 64 + kb) ^ lswz)];
#pragma unroll
                    for (int nt = 0; nt < 4; ++nt)
                        acc[mt2][nt] = __builtin_amdgcn_mfma_f32_16x16x32_bf16(
                            wf[nt][ks], bh, acc[mt2][nt], 0, 0, 0);
                }
            }
        }
        __syncthreads();  // all H0 reads complete before overwrite

        // ---- H1 = relu(acc + b1) -> bf16, write back ----
        {
            const int r0 = (lane >> 4) * 4;
#pragma unroll
            for (int mt2 = 0; mt2 < 2; ++mt2) {
                const int m = (wv * 2 + mt2) * 16 + arow;
                const unsigned rb  = (unsigned)(m * 128);
                const unsigned swz = (unsigned)((m & 7) << 4);
#pragma unroll
                for (int nt = 0; nt < 4; ++nt) {
                    float4 bv = *(const float4*)&sb1[nt * 16 + r0];
                    float v0 = fmaxf(acc[mt2][nt][0] + bv.x, 0.f);
                    float v1 = fmaxf(acc[mt2][nt][1] + bv.y, 0.f);
                    float v2 = fmaxf(acc[mt2][nt][2] + bv.z, 0.f);
                    float v3 = fmaxf(acc[mt2][nt][3] + bv.w, 0.f);
                    uint2 hp = { pk2(v0, v1), pk2(v2, v3) };
                    *(uint2*)&Hs[rb + ((unsigned)(2 * (nt * 16 + r0)) ^ swz)] = hp;
                }
            }
        }
        __syncthreads();

        // ---- layer 2 MFMA ----
        f32x4 acc2[2][4];
#pragma unroll
        for (int i = 0; i < 2; ++i)
#pragma unroll
            for (int j = 0; j < 4; ++j) acc2[i][j] = zero4;
        {
            bf16x8 wf[4][2];
#pragma unroll
            for (int nt = 0; nt < 4; ++nt)
#pragma unroll
                for (int ks = 0; ks < 2; ++ks)
                    wf[nt][ks] = *(const bf16x8*)&W2s[(nt * 16 + arow) * 128 +
                                    ((unsigned)(ks * 64 + kb) ^ lswz)];
#pragma unroll
            for (int mt2 = 0; mt2 < 2; ++mt2) {
                const unsigned rb = (unsigned)(((wv * 2 + mt2) * 16 + arow) * 128);
#pragma unroll
                for (int ks = 0; ks < 2; ++ks) {
                    bf16x8 bh = *(const bf16x8*)&Hs[rb + ((unsigned)(ks * 64 + kb) ^ lswz)];
#pragma unroll
                    for (int nt = 0; nt < 4; ++nt)
                        acc2[mt2][nt] = __builtin_amdgcn_mfma_f32_16x16x32_bf16(
                            wf[nt][ks], bh, acc2[mt2][nt], 0, 0, 0);
                }
            }
        }

        // ---- epilogue: p[m] = sum_n relu(acc2 + b2[n]) * swo[n] ----
        {
            const int r0 = (lane >> 4) * 4;
#pragma unroll
            for (int mt2 = 0; mt2 < 2; ++mt2) {
                float p = 0.f;
#pragma unroll
                for (int nt = 0; nt < 4; ++nt) {
                    float4 bv = *(const float4*)&sb2[nt * 16 + r0];
                    float4 wo = *(const float4*)&swo[nt * 16 + r0];
                    p = fmaf(fmaxf(acc2[mt2][nt][0] + bv.x, 0.f), wo.x, p);
                    p = fmaf(fmaxf(acc2[mt2][nt][1] + bv.y, 0.f), wo.y, p);
                    p = fmaf(fmaxf(acc2[mt2][nt][2] + bv.z, 0.f), wo.z, p);
                    p = fmaf(fmaxf(acc2[mt2][nt][3] + bv.w, 0.f), wo.w, p);
                }
                p += __shfl_xor(p, 16);
                p += __shfl_xor(p, 32);
                const int b = hf * 128 + (wv * 2 + mt2) * 16 + arow;
                if (lane < 16) {
                    if (atomic_mode) atomicAdd(&outbuf[b * 64 + o], p);
                    else             outbuf[(size_t)d * 256 + b] = p;
                }
            }
        }
        __syncthreads();  // layer2 H reads done before next half's layer0 writes
    }
}

// Deterministic reduction over ii: y[b,o] = bout[o] + sum_ii partial[(o*64+ii)*256 + b]
__global__ __launch_bounds__(256) void kan_reduce(
    const float* __restrict__ partial,
    const float* __restrict__ bout,
    float* __restrict__ y)
{
    const int o = blockIdx.x;    // 64
    const int b = threadIdx.x;   // 256
    float acc = bout[o];
    const float* p = partial + (size_t)o * (64 * 256) + b;
#pragma unroll
    for (int i = 0; i < 64; ++i)
        acc += p[i * 256];
    y[b * 64 + o] = acc;
}

__global__ __launch_bounds__(256) void kan_init_out(const float* __restrict__ bout,
                                                    float* __restrict__ y)
{
    const int idx = blockIdx.x * 256 + threadIdx.x;
    y[idx] = bout[idx & 63];
}

extern "C" void kernel_launch(void* const* d_in, const int* in_sizes, int n_in,
                              void* d_out, int out_size, void* d_ws, size_t ws_size,
                              hipStream_t stream) {
    const float* x    = (const float*)d_in[0];
    const float* w0   = (const float*)d_in[1];
    const float* b0   = (const float*)d_in[2];
    const float* w1   = (const float*)d_in[3];
    const float* b1   = (const float*)d_in[4];
    const float* w2   = (const float*)d_in[5];
    const float* b2   = (const float*)d_in[6];
    const float* wout = (const float*)d_in[7];
    const float* bout = (const float*)d_in[8];
    float* y = (float*)d_out;

    const size_t partial_bytes = (size_t)D_EDGES * 256 * sizeof(float); // 4 MB

    if (ws_size >= partial_bytes) {
        float* partial = (float*)d_ws;
        kan_mfma<<<D_EDGES, 256, 0, stream>>>(x, w0, b0, w1, b1, w2, b2, wout, partial, 0);
        kan_reduce<<<64, 256, 0, stream>>>(partial, bout, y);
    } else {
        kan_init_out<<<64, 256, 0, stream>>>(bout, y);
        kan_mfma<<<D_EDGES, 256, 0, stream>>>(x, w0, b0, w1, b1, w2, b2, wout, y, 1);
    }
}

// Round 4
// 43.255 us; speedup vs baseline: 6.3103x; 1.0540x over previous
//
#include <hip/hip_runtime.h>
#include <hip/hip_bf16.h>

// KAN layer, round 4: barrier-free main flow.
//  - One block per edge d; 4 waves; wave wv owns batch rows [wv*64, wv*64+63].
//  - Layer0 computed directly into MFMA B-fragments (registers, no LDS).
//  - H1 written to a wave-PRIVATE LDS region (C-layout -> B-frag relayout),
//    consumed by the same wave: s_waitcnt lgkmcnt only, no s_barrier.
//  - Single barrier per block (after weight/vector staging).
// Swapped GEMM D[n][m] = W[n][k]*H[m][k]; XOR swizzle byte ^= (row&7)<<4.

#define D_EDGES 4096

typedef __attribute__((ext_vector_type(4))) float f32x4;
typedef __attribute__((ext_vector_type(8))) short bf16x8;

__device__ __forceinline__ unsigned pk2(float a, float b) {
    __hip_bfloat162 h = __float22bfloat162_rn(float2{a, b});
    return *reinterpret_cast<unsigned*>(&h);
}

union BFr { unsigned u[4]; bf16x8 v; };

__global__ __launch_bounds__(256, 3) void kan_mfma(
    const float* __restrict__ x,     // (256, 64)
    const float* __restrict__ w0g,   // (D, 64)
    const float* __restrict__ b0g,   // (D, 64)
    const float* __restrict__ w1g,   // (D, 64, 64)
    const float* __restrict__ b1g,   // (D, 64)
    const float* __restrict__ w2g,   // (D, 64, 64)
    const float* __restrict__ b2g,   // (D, 64)
    const float* __restrict__ woutg, // (64, 4096)
    float* __restrict__ outbuf,      // partial (D,256) or y (256,64)
    int atomic_mode)
{
    const int d = blockIdx.x, o = d >> 6, ii = d & 63;
    const int t = threadIdx.x;
    const int lane = t & 63, wv = t >> 6;

    __shared__ __align__(16) unsigned char W1s[64 * 128];   // [n][k] bf16, swizzled
    __shared__ __align__(16) unsigned char W2s[64 * 128];
    __shared__ __align__(16) unsigned char Hs[256 * 128];   // H1 [m][k] bf16, swizzled; wave-private rows
    __shared__ __align__(16) float sx[256];
    __shared__ __align__(16) float sw0[64], sb0[64], sb1[64], sb2[64], swo[64];

    // ---- stage W1, W2 -> bf16, swizzled (16 elems / thread / matrix) ----
    {
        const int orow = t >> 2, q = t & 3;
        const unsigned swz  = (unsigned)((orow & 7) << 4);
        const unsigned base = (unsigned)(orow * 128);
        const float* s1 = w1g + (size_t)d * 4096 + orow * 64 + q * 16;
        const float* s2 = w2g + (size_t)d * 4096 + orow * 64 + q * 16;

        float4 a0 = ((const float4*)s1)[0], a1 = ((const float4*)s1)[1];
        float4 a2 = ((const float4*)s1)[2], a3 = ((const float4*)s1)[3];
        uint4 u0 = { pk2(a0.x, a0.y), pk2(a0.z, a0.w), pk2(a1.x, a1.y), pk2(a1.z, a1.w) };
        uint4 u1 = { pk2(a2.x, a2.y), pk2(a2.z, a2.w), pk2(a3.x, a3.y), pk2(a3.z, a3.w) };
        *(uint4*)&W1s[base + ((unsigned)(q * 32)      ^ swz)] = u0;
        *(uint4*)&W1s[base + ((unsigned)(q * 32 + 16) ^ swz)] = u1;

        a0 = ((const float4*)s2)[0]; a1 = ((const float4*)s2)[1];
        a2 = ((const float4*)s2)[2]; a3 = ((const float4*)s2)[3];
        uint4 v0 = { pk2(a0.x, a0.y), pk2(a0.z, a0.w), pk2(a1.x, a1.y), pk2(a1.z, a1.w) };
        uint4 v1 = { pk2(a2.x, a2.y), pk2(a2.z, a2.w), pk2(a3.x, a3.y), pk2(a3.z, a3.w) };
        *(uint4*)&W2s[base + ((unsigned)(q * 32)      ^ swz)] = v0;
        *(uint4*)&W2s[base + ((unsigned)(q * 32 + 16) ^ swz)] = v1;
    }
    sx[t] = x[t * 64 + ii];
    if (t < 64) {
        sw0[t] = w0g[(size_t)d * 64 + t];
        sb0[t] = b0g[(size_t)d * 64 + t];
        sb1[t] = b1g[(size_t)d * 64 + t];
        sb2[t] = b2g[(size_t)d * 64 + t];
        swo[t] = woutg[(size_t)o * 4096 + ii * 64 + t];
    }
    __syncthreads();   // the only block-wide barrier

    const int arow = lane & 15;
    const int kb   = (lane >> 4) * 16;     // byte offset of this lane's 8 k-elems
    const int g8   = (lane >> 4) * 8;      // element offset
    const unsigned lswz = (unsigned)((lane & 7) << 4);
    const int mbase = wv * 64;
    const int r0 = (lane >> 4) * 4;
    const f32x4 zero4 = { 0.f, 0.f, 0.f, 0.f };

    // ---- A-fragments for layer 1 ----
    bf16x8 wf1[4][2];
#pragma unroll
    for (int nt = 0; nt < 4; ++nt)
#pragma unroll
        for (int ks = 0; ks < 2; ++ks)
            wf1[nt][ks] = *(const bf16x8*)&W1s[(nt * 16 + arow) * 128 +
                            ((unsigned)(ks * 64 + kb) ^ lswz)];

    // ---- hoist w0/b0 slices for this lane's k-positions ----
    float4 w0v[2][2], b0v[2][2];
#pragma unroll
    for (int ks = 0; ks < 2; ++ks) {
        const int k0 = ks * 32 + g8;
        w0v[ks][0] = *(const float4*)&sw0[k0];
        w0v[ks][1] = *(const float4*)&sw0[k0 + 4];
        b0v[ks][0] = *(const float4*)&sb0[k0];
        b0v[ks][1] = *(const float4*)&sb0[k0 + 4];
    }

    // ---- layer 1: B-frags computed in registers, MFMA accumulate ----
    f32x4 acc[4][4];
#pragma unroll
    for (int i = 0; i < 4; ++i)
#pragma unroll
        for (int j = 0; j < 4; ++j) acc[i][j] = zero4;

#pragma unroll
    for (int mti = 0; mti < 4; ++mti) {
        const float xm = sx[mbase + mti * 16 + arow];
#pragma unroll
        for (int ks = 0; ks < 2; ++ks) {
            float4 wa = w0v[ks][0], wb = w0v[ks][1];
            float4 ba = b0v[ks][0], bb = b0v[ks][1];
            float v0 = fmaxf(fmaf(xm, wa.x, ba.x), 0.f);
            float v1 = fmaxf(fmaf(xm, wa.y, ba.y), 0.f);
            float v2 = fmaxf(fmaf(xm, wa.z, ba.z), 0.f);
            float v3 = fmaxf(fmaf(xm, wa.w, ba.w), 0.f);
            float v4 = fmaxf(fmaf(xm, wb.x, bb.x), 0.f);
            float v5 = fmaxf(fmaf(xm, wb.y, bb.y), 0.f);
            float v6 = fmaxf(fmaf(xm, wb.z, bb.z), 0.f);
            float v7 = fmaxf(fmaf(xm, wb.w, bb.w), 0.f);
            BFr bh;
            bh.u[0] = pk2(v0, v1); bh.u[1] = pk2(v2, v3);
            bh.u[2] = pk2(v4, v5); bh.u[3] = pk2(v6, v7);
#pragma unroll
            for (int nt = 0; nt < 4; ++nt)
                acc[mti][nt] = __builtin_amdgcn_mfma_f32_16x16x32_bf16(
                    wf1[nt][ks], bh.v, acc[mti][nt], 0, 0, 0);
        }
    }

    // ---- H1 = relu(acc + b1) -> wave-private LDS rows (C-layout -> [m][k]) ----
#pragma unroll
    for (int mti = 0; mti < 4; ++mti) {
        const unsigned rb = (unsigned)((mbase + mti * 16 + arow) * 128);
#pragma unroll
        for (int nt = 0; nt < 4; ++nt) {
            float4 bv = *(const float4*)&sb1[nt * 16 + r0];
            float v0 = fmaxf(acc[mti][nt][0] + bv.x, 0.f);
            float v1 = fmaxf(acc[mti][nt][1] + bv.y, 0.f);
            float v2 = fmaxf(acc[mti][nt][2] + bv.z, 0.f);
            float v3 = fmaxf(acc[mti][nt][3] + bv.w, 0.f);
            uint2 hp = { pk2(v0, v1), pk2(v2, v3) };
            *(uint2*)&Hs[rb + ((unsigned)(2 * (nt * 16 + r0)) ^ lswz)] = hp;
        }
    }

    // same-wave producer/consumer: drain LDS writes, no barrier needed
    asm volatile("s_waitcnt lgkmcnt(0)" ::: "memory");

    // ---- A-fragments for layer 2 ----
    bf16x8 wf2[4][2];
#pragma unroll
    for (int nt = 0; nt < 4; ++nt)
#pragma unroll
        for (int ks = 0; ks < 2; ++ks)
            wf2[nt][ks] = *(const bf16x8*)&W2s[(nt * 16 + arow) * 128 +
                            ((unsigned)(ks * 64 + kb) ^ lswz)];

    // ---- layer 2: read own H1 rows as B-frags, MFMA (reuse acc) ----
#pragma unroll
    for (int i = 0; i < 4; ++i)
#pragma unroll
        for (int j = 0; j < 4; ++j) acc[i][j] = zero4;

#pragma unroll
    for (int mti = 0; mti < 4; ++mti) {
        const unsigned rb = (unsigned)((mbase + mti * 16 + arow) * 128);
#pragma unroll
        for (int ks = 0; ks < 2; ++ks) {
            bf16x8 bh = *(const bf16x8*)&Hs[rb + ((unsigned)(ks * 64 + kb) ^ lswz)];
#pragma unroll
            for (int nt = 0; nt < 4; ++nt)
                acc[mti][nt] = __builtin_amdgcn_mfma_f32_16x16x32_bf16(
                    wf2[nt][ks], bh, acc[mti][nt], 0, 0, 0);
        }
    }

    // ---- epilogue: p[m] = sum_n relu(acc + b2[n]) * swo[n] ----
#pragma unroll
    for (int mti = 0; mti < 4; ++mti) {
        float p = 0.f;
#pragma unroll
        for (int nt = 0; nt < 4; ++nt) {
            float4 bv = *(const float4*)&sb2[nt * 16 + r0];
            float4 wo = *(const float4*)&swo[nt * 16 + r0];
            p = fmaf(fmaxf(acc[mti][nt][0] + bv.x, 0.f), wo.x, p);
            p = fmaf(fmaxf(acc[mti][nt][1] + bv.y, 0.f), wo.y, p);
            p = fmaf(fmaxf(acc[mti][nt][2] + bv.z, 0.f), wo.z, p);
            p = fmaf(fmaxf(acc[mti][nt][3] + bv.w, 0.f), wo.w, p);
        }
        p += __shfl_xor(p, 16);
        p += __shfl_xor(p, 32);
        const int b = mbase + mti * 16 + arow;
        if (lane < 16) {
            if (atomic_mode) atomicAdd(&outbuf[b * 64 + o], p);
            else             outbuf[(size_t)d * 256 + b] = p;
        }
    }
}

// Deterministic reduction over ii: y[b,o] = bout[o] + sum_ii partial[(o*64+ii)*256 + b]
__global__ __launch_bounds__(256) void kan_reduce(
    const float* __restrict__ partial,
    const float* __restrict__ bout,
    float* __restrict__ y)
{
    const int o = blockIdx.x;    // 64
    const int b = threadIdx.x;   // 256
    float acc = bout[o];
    const float* p = partial + (size_t)o * (64 * 256) + b;
#pragma unroll
    for (int i = 0; i < 64; ++i)
        acc += p[i * 256];
    y[b * 64 + o] = acc;
}

__global__ __launch_bounds__(256) void kan_init_out(const float* __restrict__ bout,
                                                    float* __restrict__ y)
{
    const int idx = blockIdx.x * 256 + threadIdx.x;
    y[idx] = bout[idx & 63];
}

extern "C" void kernel_launch(void* const* d_in, const int* in_sizes, int n_in,
                              void* d_out, int out_size, void* d_ws, size_t ws_size,
                              hipStream_t stream) {
    const float* x    = (const float*)d_in[0];
    const float* w0   = (const float*)d_in[1];
    const float* b0   = (const float*)d_in[2];
    const float* w1   = (const float*)d_in[3];
    const float* b1   = (const float*)d_in[4];
    const float* w2   = (const float*)d_in[5];
    const float* b2   = (const float*)d_in[6];
    const float* wout = (const float*)d_in[7];
    const float* bout = (const float*)d_in[8];
    float* y = (float*)d_out;

    const size_t partial_bytes = (size_t)D_EDGES * 256 * sizeof(float); // 4 MB

    if (ws_size >= partial_bytes) {
        float* partial = (float*)d_ws;
        kan_mfma<<<D_EDGES, 256, 0, stream>>>(x, w0, b0, w1, b1, w2, b2, wout, partial, 0);
        kan_reduce<<<64, 256, 0, stream>>>(partial, bout, y);
    } else {
        kan_init_out<<<64, 256, 0, stream>>>(bout, y);
        kan_mfma<<<D_EDGES, 256, 0, stream>>>(x, w0, b0, w1, b1, w2, b2, wout, y, 1);
    }
}